// Round 1
// baseline (478.796 us; speedup 1.0000x reference)
//
#include <hip/hip_runtime.h>
#include <hip/hip_bf16.h>
#include <stdint.h>

#define B_ 64
#define N_ 4096
#define D_ 128
#define S_ 7
#define HID_ 256
#define EPS_ 1e-8f
#define LN_EPS_ 1e-5f
#define LDW 136   // padded LDS leading dim (bf16 elems): breaks pow2 bank stride

typedef float  f32x4  __attribute__((ext_vector_type(4)));
typedef __bf16 bf16x8 __attribute__((ext_vector_type(8)));

__device__ __forceinline__ float bfbits2f(uint32_t u) { return __uint_as_float(u << 16); }
__device__ __forceinline__ uint16_t f2bfbits(float f) {
    uint32_t x = __float_as_uint(f);
    return (uint16_t)((x + 0x7fffu + ((x >> 16) & 1u)) >> 16);  // RNE
}

// ---------------------------------------------------------------------------
// K0: once-per-call prep: slots = mu + (softplus(logsigma)+1e-5)*noise,
//     Wcat = bf16([Wk; Wv]) (256x128), zero the padded q buffer (64x16x128).
// ---------------------------------------------------------------------------
__global__ void k_prep(const float* __restrict__ noise, const float* __restrict__ Wk,
                       const float* __restrict__ Wv, const float* __restrict__ mu,
                       const float* __restrict__ logsigma,
                       uint16_t* __restrict__ Wcat, float* __restrict__ slots,
                       uint16_t* __restrict__ qbf) {
    int tid = blockIdx.x * 256 + threadIdx.x;
    if (tid < B_ * 16 * D_) qbf[tid] = 0;
    if (tid < B_ * S_ * D_) {
        int d = tid & (D_ - 1);
        float sc = log1pf(__expf(logsigma[d])) + 1e-5f;
        slots[tid] = mu[d] + sc * noise[tid];
    }
    if (tid < 2 * D_ * D_) {
        int o = tid >> 7, j = tid & 127;
        float w = (o < D_) ? Wk[o * D_ + j] : Wv[(o - D_) * D_ + j];
        Wcat[tid] = f2bfbits(w);
    }
}

// ---------------------------------------------------------------------------
// K1: LN(x) rows -> bf16, then MFMA GEMM vs [Wk;Wv] -> kbf, vbf (bf16).
// Block: 256 thr (4 waves), 64 rows x 256 cols, K=128.
// ---------------------------------------------------------------------------
__global__ __launch_bounds__(256) void k_proj(
    const float* __restrict__ x, const uint16_t* __restrict__ Wcat,
    const float* __restrict__ lng, const float* __restrict__ lnb,
    uint16_t* __restrict__ kbf, uint16_t* __restrict__ vbf) {
    __shared__ uint16_t xs[64 * LDW];    // 17408 B
    __shared__ uint16_t wsm[128 * LDW];  // 34816 B
    const int t = threadIdx.x;
    const int wv = t >> 6, lane = t & 63;
    const long row0 = (long)blockIdx.x * 64;

    const float g0 = lng[2 * lane], g1 = lng[2 * lane + 1];
    const float bb0 = lnb[2 * lane], bb1 = lnb[2 * lane + 1];
    #pragma unroll 4
    for (int i = 0; i < 16; ++i) {
        int r = wv * 16 + i;
        float2 xv = *(const float2*)(x + (row0 + r) * 128 + 2 * lane);
        float s = xv.x + xv.y, sq = xv.x * xv.x + xv.y * xv.y;
        #pragma unroll
        for (int m = 1; m < 64; m <<= 1) { s += __shfl_xor(s, m); sq += __shfl_xor(sq, m); }
        float mean = s * (1.0f / 128.0f);
        float var = sq * (1.0f / 128.0f) - mean * mean;
        float rs = rsqrtf(var + LN_EPS_);
        uint32_t p = (uint32_t)f2bfbits((xv.x - mean) * rs * g0 + bb0)
                   | ((uint32_t)f2bfbits((xv.y - mean) * rs * g1 + bb1) << 16);
        *(uint32_t*)(xs + r * LDW + 2 * lane) = p;
    }

    const int lm = lane & 15, qd = lane >> 4;
    const int arow = wv * 16 + lm;
    const f32x4 vzero = {0.f, 0.f, 0.f, 0.f};
    for (int half = 0; half < 2; ++half) {
        __syncthreads();  // xs ready / previous half's reads of wsm done
        {
            int r = t >> 1, c0 = (t & 1) * 64;
            const uint4* src = (const uint4*)(Wcat + (half * 128 + r) * 128 + c0);
            uint4* dst = (uint4*)(wsm + r * LDW + c0);
            #pragma unroll
            for (int i = 0; i < 8; ++i) dst[i] = src[i];
        }
        __syncthreads();
        f32x4 acc[8];
        #pragma unroll
        for (int i = 0; i < 8; ++i) acc[i] = vzero;
        #pragma unroll
        for (int k0 = 0; k0 < 128; k0 += 32) {
            bf16x8 a = *(const bf16x8*)(xs + arow * LDW + k0 + qd * 8);
            #pragma unroll
            for (int nt = 0; nt < 8; ++nt) {
                bf16x8 bq = *(const bf16x8*)(wsm + (nt * 16 + lm) * LDW + k0 + qd * 8);
                acc[nt] = __builtin_amdgcn_mfma_f32_16x16x32_bf16(a, bq, acc[nt], 0, 0, 0);
            }
        }
        uint16_t* __restrict__ outp = half ? vbf : kbf;
        #pragma unroll
        for (int nt = 0; nt < 8; ++nt) {
            int col = nt * 16 + lm;
            #pragma unroll
            for (int r = 0; r < 4; ++r) {
                long grow = row0 + wv * 16 + qd * 4 + r;
                outp[grow * 128 + col] = f2bfbits(acc[nt][r]);
            }
        }
    }
}

// ---------------------------------------------------------------------------
// K2: per (b,s): sn = LN(slots); q = (sn @ Wq^T) * D^-1/2 -> bf16 (padded rows
//     7..15 stay zero). Also zeroes upraw row + colsum for this iteration.
// ---------------------------------------------------------------------------
__global__ __launch_bounds__(128) void k_slotq(
    const float* __restrict__ slots, const float* __restrict__ Wq,
    const float* __restrict__ g, const float* __restrict__ bt,
    uint16_t* __restrict__ qbf, float* __restrict__ colsum, float* __restrict__ upraw) {
    int row = blockIdx.x;  // b*7 + s
    int b = row / 7, s = row - b * 7;
    int t = threadIdx.x;
    __shared__ float sn[128];
    __shared__ float red[2];
    float v = slots[row * 128 + t];
    float sv = v;
    #pragma unroll
    for (int m = 1; m < 64; m <<= 1) sv += __shfl_xor(sv, m);
    if ((t & 63) == 0) red[t >> 6] = sv;
    __syncthreads();
    float mean = (red[0] + red[1]) * (1.0f / 128.0f);
    __syncthreads();
    float dv = v - mean, sq = dv * dv;
    #pragma unroll
    for (int m = 1; m < 64; m <<= 1) sq += __shfl_xor(sq, m);
    if ((t & 63) == 0) red[t >> 6] = sq;
    __syncthreads();
    float var = (red[0] + red[1]) * (1.0f / 128.0f);
    sn[t] = dv * rsqrtf(var + LN_EPS_) * g[t] + bt[t];
    __syncthreads();
    const float4* wr = (const float4*)(Wq + t * 128);
    float acc = 0.f;
    #pragma unroll 8
    for (int j = 0; j < 32; ++j) {
        float4 w = wr[j];
        float4 s4 = *(const float4*)(sn + 4 * j);
        acc += w.x * s4.x + w.y * s4.y + w.z * s4.z + w.w * s4.w;
    }
    qbf[(b * 16 + s) * 128 + t] = f2bfbits(acc * 0.08838834764831843f);  // 1/sqrt(128)
    upraw[row * 128 + t] = 0.f;
    if (t == 0) colsum[row] = 0.f;
}

// ---------------------------------------------------------------------------
// K3 (fused): scores via MFMA (A = k rows from global, B = padded q bf16),
// softmax over S=7 (cross-lane in 16-lane groups), attn kept in LDS, then
// updates partial  U[s][d] += attn * v  and colsum accumulation via atomics.
// Grid: (b, chunk-of-256-rows); 4 waves x 64 rows.
// ---------------------------------------------------------------------------
__global__ __launch_bounds__(256) void k_attn(
    const uint16_t* __restrict__ kbf, const uint16_t* __restrict__ vbf,
    const uint16_t* __restrict__ qbf,
    float* __restrict__ colsum, float* __restrict__ upraw) {
    __shared__ float als[4][64][8];    // per-wave attn tile (softmax+eps)
    __shared__ float part[4][7][128];  // per-wave update partials
    __shared__ float bsum[7];
    const int t = threadIdx.x, wv = t >> 6, lane = t & 63;
    const int lm = lane & 15, qd = lane >> 4;
    const int b = blockIdx.x >> 4, chunk = blockIdx.x & 15;
    const long nbase = (long)b * N_ + chunk * 256 + wv * 64;
    if (t < 7) bsum[t] = 0.f;
    __syncthreads();

    bf16x8 bq[4];
    #pragma unroll
    for (int k0 = 0; k0 < 4; ++k0)
        bq[k0] = *(const bf16x8*)(qbf + b * 2048 + lm * 128 + k0 * 32 + qd * 8);

    const f32x4 vzero = {0.f, 0.f, 0.f, 0.f};
    float csl = 0.f;  // per-lane colsum contribution for slot lm
    #pragma unroll
    for (int mt = 0; mt < 4; ++mt) {
        f32x4 acc = vzero;
        long rbase = nbase + mt * 16;
        #pragma unroll
        for (int k0 = 0; k0 < 4; ++k0) {
            bf16x8 a = *(const bf16x8*)(kbf + (rbase + lm) * 128 + k0 * 32 + qd * 8);
            acc = __builtin_amdgcn_mfma_f32_16x16x32_bf16(a, bq[k0], acc, 0, 0, 0);
        }
        #pragma unroll
        for (int r = 0; r < 4; ++r) {
            float sc = acc[r];
            float scm = (lm < 7) ? sc : -1e30f;
            #pragma unroll
            for (int m = 1; m < 16; m <<= 1) scm = fmaxf(scm, __shfl_xor(scm, m));
            float e = (lm < 7) ? __expf(sc - scm) : 0.f;
            float tot = e;
            #pragma unroll
            for (int m = 1; m < 16; m <<= 1) tot += __shfl_xor(tot, m);
            float a_ = e / tot + EPS_;
            int lrow = mt * 16 + qd * 4 + r;
            if (lm < 7) { als[wv][lrow][lm] = a_; csl += a_; }
        }
    }
    if (lm < 7) atomicAdd(&bsum[lm], csl);

    // v-weighted accumulation: lane handles d = 2*lane, 2*lane+1
    float accv[14];
    #pragma unroll
    for (int i = 0; i < 14; ++i) accv[i] = 0.f;
    for (int i = 0; i < 64; ++i) {
        long row = nbase + i;
        uint32_t vvb = *(const uint32_t*)(vbf + row * 128 + 2 * lane);
        float v0 = bfbits2f(vvb & 0xffffu), v1 = bfbits2f(vvb >> 16);
        #pragma unroll
        for (int s = 0; s < 7; ++s) {
            float a_ = als[wv][i][s];
            accv[2 * s]     += a_ * v0;
            accv[2 * s + 1] += a_ * v1;
        }
    }
    #pragma unroll
    for (int s = 0; s < 7; ++s) {
        part[wv][s][2 * lane]     = accv[2 * s];
        part[wv][s][2 * lane + 1] = accv[2 * s + 1];
    }
    __syncthreads();
    if (t < 128) {
        #pragma unroll
        for (int s = 0; s < 7; ++s) {
            float vs = part[0][s][t] + part[1][s][t] + part[2][s][t] + part[3][s][t];
            atomicAdd(&upraw[(b * 7 + s) * 128 + t], vs);
        }
    }
    if (t < 7) atomicAdd(&colsum[b * 7 + t], bsum[t]);
}

// ---------------------------------------------------------------------------
// K4: per (b,s) row: u = upraw/colsum; GRU(u, h=slots); LN; slots = sl + MLP(sl)
// ---------------------------------------------------------------------------
__global__ __launch_bounds__(128) void k_gru_mlp(
    const float* __restrict__ upraw, const float* __restrict__ colsum,
    const float* __restrict__ slots_in,
    const float* __restrict__ Wih, const float* __restrict__ Whh,
    const float* __restrict__ bih, const float* __restrict__ bhh,
    const float* __restrict__ gm, const float* __restrict__ bm,
    const float* __restrict__ W1, const float* __restrict__ b1,
    const float* __restrict__ W2, const float* __restrict__ b2,
    float* __restrict__ dst) {
    int row = blockIdx.x, t = threadIdx.x;
    __shared__ float su[128], sh[128], ssl[128], shid[256];
    __shared__ float red[2];
    float inv = 1.0f / colsum[row];
    float u = upraw[row * 128 + t] * inv;
    float h = slots_in[row * 128 + t];
    su[t] = u; sh[t] = h;
    __syncthreads();
    float gx[3], gh[3];
    #pragma unroll
    for (int p = 0; p < 3; ++p) {
        int o = p * 128 + t;
        const float4* wi = (const float4*)(Wih + o * 128);
        const float4* wh = (const float4*)(Whh + o * 128);
        float ax = 0.f, ah = 0.f;
        #pragma unroll 8
        for (int j = 0; j < 32; ++j) {
            float4 a = wi[j], bb = wh[j];
            float4 uu = *(const float4*)(su + 4 * j);
            float4 hh = *(const float4*)(sh + 4 * j);
            ax += a.x * uu.x + a.y * uu.y + a.z * uu.z + a.w * uu.w;
            ah += bb.x * hh.x + bb.y * hh.y + bb.z * hh.z + bb.w * hh.w;
        }
        gx[p] = ax + bih[o];
        gh[p] = ah + bhh[o];
    }
    float r = 1.f / (1.f + __expf(-(gx[0] + gh[0])));
    float z = 1.f / (1.f + __expf(-(gx[1] + gh[1])));
    float n = tanhf(gx[2] + r * gh[2]);
    float hn = (1.f - z) * n + z * h;
    // LayerNorm(hn)
    float sv = hn;
    #pragma unroll
    for (int m = 1; m < 64; m <<= 1) sv += __shfl_xor(sv, m);
    if ((t & 63) == 0) red[t >> 6] = sv;
    __syncthreads();
    float mean = (red[0] + red[1]) * (1.0f / 128.0f);
    __syncthreads();
    float dv = hn - mean, sq = dv * dv;
    #pragma unroll
    for (int m = 1; m < 64; m <<= 1) sq += __shfl_xor(sq, m);
    if ((t & 63) == 0) red[t >> 6] = sq;
    __syncthreads();
    float var = (red[0] + red[1]) * (1.0f / 128.0f);
    float sl = dv * rsqrtf(var + LN_EPS_) * gm[t] + bm[t];
    ssl[t] = sl;
    __syncthreads();
    #pragma unroll
    for (int p = 0; p < 2; ++p) {
        int o = p * 128 + t;
        const float4* w1r = (const float4*)(W1 + o * 128);
        float a1 = 0.f;
        #pragma unroll 8
        for (int j = 0; j < 32; ++j) {
            float4 w = w1r[j];
            float4 s4 = *(const float4*)(ssl + 4 * j);
            a1 += w.x * s4.x + w.y * s4.y + w.z * s4.z + w.w * s4.w;
        }
        shid[o] = fmaxf(a1 + b1[o], 0.f);
    }
    __syncthreads();
    const float4* w2r = (const float4*)(W2 + t * 256);
    float a2 = 0.f;
    #pragma unroll 8
    for (int j = 0; j < 64; ++j) {
        float4 w = w2r[j];
        float4 h4 = *(const float4*)(shid + 4 * j);
        a2 += w.x * h4.x + w.y * h4.y + w.z * h4.z + w.w * h4.w;
    }
    dst[row * 128 + t] = sl + a2 + b2[t];
}

// ---------------------------------------------------------------------------
extern "C" void kernel_launch(void* const* d_in, const int* in_sizes, int n_in,
                              void* d_out, int out_size, void* d_ws, size_t ws_size,
                              hipStream_t stream) {
    const float* x    = (const float*)d_in[0];
    const float* nz   = (const float*)d_in[1];
    const float* Wq   = (const float*)d_in[2];
    const float* Wk   = (const float*)d_in[3];
    const float* Wv   = (const float*)d_in[4];
    const float* ling = (const float*)d_in[5];
    const float* linb = (const float*)d_in[6];
    const float* lsg  = (const float*)d_in[7];
    const float* lsb  = (const float*)d_in[8];
    const float* lmg  = (const float*)d_in[9];
    const float* lmb  = (const float*)d_in[10];
    const float* Wih  = (const float*)d_in[11];
    const float* Whh  = (const float*)d_in[12];
    const float* bih  = (const float*)d_in[13];
    const float* bhh  = (const float*)d_in[14];
    const float* W1   = (const float*)d_in[15];
    const float* b1   = (const float*)d_in[16];
    const float* W2   = (const float*)d_in[17];
    const float* b2   = (const float*)d_in[18];
    const float* mu   = (const float*)d_in[19];
    const float* lsig = (const float*)d_in[20];

    char* wsb = (char*)d_ws;
    uint16_t* kbf  = (uint16_t*)(wsb);                        // 67108864 B
    uint16_t* vbf  = (uint16_t*)(wsb + (size_t)67108864);     // 67108864 B
    uint16_t* Wcat = (uint16_t*)(wsb + (size_t)134217728);    // 65536 B
    uint16_t* qbf  = (uint16_t*)(wsb + (size_t)134283264);    // 262144 B (64x16x128 bf16)
    float*    slots= (float*)  (wsb + (size_t)134545408);     // 229376 B
    float*    csum = (float*)  (wsb + (size_t)134774784);     // 2048 B
    float*    upraw= (float*)  (wsb + (size_t)134776832);     // 229376 B  (end ~135 MB)

    k_prep<<<512, 256, 0, stream>>>(nz, Wk, Wv, mu, lsig, Wcat, slots, qbf);
    k_proj<<<4096, 256, 0, stream>>>(x, Wcat, ling, linb, kbf, vbf);
    for (int it = 0; it < 3; ++it) {
        float* dst = (it == 2) ? (float*)d_out : slots;
        k_slotq<<<448, 128, 0, stream>>>(slots, Wq, lsg, lsb, qbf, csum, upraw);
        k_attn<<<1024, 256, 0, stream>>>(kbf, vbf, qbf, csum, upraw);
        k_gru_mlp<<<448, 128, 0, stream>>>(upraw, csum, slots, Wih, Whh, bih, bhh,
                                           lmg, lmb, W1, b1, W2, b2, dst);
    }
}